// Round 7
// baseline (129.336 us; speedup 1.0000x reference)
//
#include <hip/hip_runtime.h>

// GeometricAttention: B=4, N=256, FDIM=256, REL=16, H=8, D=32
//   K[b,i,j] = Kn[b,j] + rel[b,i,j] @ Wk_r          (Kn = nf@Wk_f + bk)
//   scores   = Q.Kn^T + Qr.rel^T                     (Qr = per-head Q @ Wk_r^T)
//   sum_j attn*V = attn@Vn + (attn@rel)@Wv_r         (Vn = nf@Wv_f + bv)
// Round 7: ONE kernel. 512 blocks x 512 thr (exactly 2 blocks/CU, all
// co-resident), device-scope spin barrier between projection and attention.
// Block's own Q rows / nf rows never leave LDS; rel staging + qr overlap the
// barrier spin. Barrier counter in ws, zeroed per call via hipMemsetAsync.

#define BB 4
#define NN 256
#define FD 256
#define RL 16
#define NH 8
#define HD 32
#define NBLK 512

// ws layout (float offsets)
#define OFF_KN   0                        // ushort KnT[b][f][j]   (512 KB)
#define OFF_VN   (BB*NN*FD/2)             // ushort Vn[b][j][c]    (512 KB)
#define OFF_WO   (OFF_VN + BB*NN*FD/2)    // uint WoP[128][256]    (128 KB)
#define OFF_SYNC (OFF_WO + FD*FD/2)       // unsigned counter

#define ATP 260   // at[] row stride (floats)
#define RLT 262   // rldsT row stride; 262%32=6 -> 16 r-lanes hit distinct banks

static __device__ __forceinline__ unsigned short f2bf(float x) {
  unsigned int u = __float_as_uint(x);
  unsigned int r = (u + 0x7fffu + ((u >> 16) & 1u)) >> 16;   // RNE
  return (unsigned short)r;
}
static __device__ __forceinline__ float bf2f(unsigned short h) {
  return __uint_as_float(((unsigned int)h) << 16);
}

__global__ __launch_bounds__(512, 4) void k_fused(
    const float* __restrict__ nf, const float* __restrict__ rel,
    const float* __restrict__ Wq, const float* __restrict__ bq,
    const float* __restrict__ Wk, const float* __restrict__ bk,
    const float* __restrict__ Wv, const float* __restrict__ bv,
    const float* __restrict__ Wo, const float* __restrict__ bo,
    float* __restrict__ out, float* __restrict__ ws) {
  const unsigned short* KnB = (const unsigned short*)(ws + OFF_KN);
  const unsigned short* VnB = (const unsigned short*)(ws + OFF_VN);
  const unsigned int* WoP = (const unsigned int*)(ws + OFF_WO);
  unsigned int* syncp = (unsigned int*)(ws + OFF_SYNC);

  // XCD-chunked swizzle (bijective, 512 % 8 == 0)
  const int bid = (blockIdx.x & 7) * 64 + (blockIdx.x >> 3);
  const int b  = bid >> 7;
  const int i0 = (bid & 127) * 2;
  const int tid = threadIdx.x;
  const int l = tid & 63, w = tid >> 6;

  __shared__ float nfT[FD][2];                         // 2 KB   [k][r]
  __shared__ float q[2][FD];                           // 2 KB   scaled
  __shared__ float qrs[2][NH * RL];                    // 1 KB
  __shared__ __align__(16) float rldsT[2 * RL * RLT];  // 32.8 KB (aliased later)
  __shared__ __align__(16) float at[2 * NH * ATP];     // 16.3 KB (red during proj)
  __shared__ float ar[2][NH * RL];                     // 1 KB
  float* red  = at;                                    // [6][256] proj reduce
  float* part = rldsT;                                 // [16][256] after phase C
  float* wvT  = rldsT + 16 * 256;                      // [256][2]

  // ======== PROJECTION: this block's 2 rows through Wq/Wk/Wv ========
  {
    const int r0 = tid >> 8, k0 = tid & 255;
    nfT[k0][r0] = nf[(b * NN + i0 + r0) * FD + k0];
  }
  __syncthreads();
  const int col = tid & 255, half = tid >> 8;
  float aq0=0.f,aq1=0.f,ak0=0.f,ak1=0.f,av0=0.f,av1=0.f;
  {
    const float* wqp = Wq + (half * 128) * FD + col;
    const float* wkp = Wk + (half * 128) * FD + col;
    const float* wvp = Wv + (half * 128) * FD + col;
    const float* np  = &nfT[half * 128][0];
    #pragma unroll 8
    for (int kk = 0; kk < 128; ++kk) {
      float2 nv = *(const float2*)&np[kk * 2];
      float wq_ = wqp[kk * FD], wk_ = wkp[kk * FD], wv_ = wvp[kk * FD];
      aq0 += nv.x * wq_; aq1 += nv.y * wq_;
      ak0 += nv.x * wk_; ak1 += nv.y * wk_;
      av0 += nv.x * wv_; av1 += nv.y * wv_;
    }
  }
  __syncthreads();                 // nfT k-loop reads done; red aliases at
  if (half) {
    red[0*256+col]=aq0; red[1*256+col]=aq1;
    red[2*256+col]=ak0; red[3*256+col]=ak1;
    red[4*256+col]=av0; red[5*256+col]=av1;
  }
  __syncthreads();
  if (!half) {
    const float scale = 0.17677669529663687f;   // 1/sqrt(32)
    aq0 += red[0*256+col]; aq1 += red[1*256+col];
    ak0 += red[2*256+col]; ak1 += red[3*256+col];
    av0 += red[4*256+col]; av1 += red[5*256+col];
    q[0][col] = (aq0 + bq[col]) * scale;
    q[1][col] = (aq1 + bq[col]) * scale;
    const float bkc = bk[col];
    unsigned int kp = (unsigned int)f2bf(ak0 + bkc)
                    | ((unsigned int)f2bf(ak1 + bkc) << 16);
    ((unsigned int*)(ws + OFF_KN))[((size_t)b * FD + col) * (NN/2) + (i0 >> 1)] = kp;
    const float bvc = bv[col];
    unsigned short* vp = (unsigned short*)(ws + OFF_VN);
    vp[((size_t)b * NN + i0)     * FD + col] = f2bf(av0 + bvc);
    vp[((size_t)b * NN + i0 + 1) * FD + col] = f2bf(av1 + bvc);
  }
  // WoP pack: first 128 raw blocks, 2 Wo rows each
  if (blockIdx.x < 128 && tid < 256) {
    const int k2 = blockIdx.x;
    unsigned int lo = f2bf(Wo[(2 * k2) * FD + tid]);
    unsigned int hi = f2bf(Wo[(2 * k2 + 1) * FD + tid]);
    ((unsigned int*)(ws + OFF_WO))[k2 * FD + tid] = lo | (hi << 16);
  }
  __syncthreads();                 // q visible block-wide

  // ---- pre-barrier (overlaps other blocks' projections):
  // qr[ii][h][r] = q[ii][h*32..] . Wk_r rows
  if (tid < 256) {
    const int ii = tid >> 7, h = (tid >> 4) & 7, r = tid & 15;
    const float* wrow = Wk + (FD + r) * FD + h * HD;
    const float* qq = &q[ii][h * HD];
    float a = 0.f;
    #pragma unroll
    for (int d = 0; d < HD; ++d) a += qq[d] * wrow[d];
    qrs[ii][h * RL + r] = a;
  }
  // stage rel transposed: wave w -> row ii = w>>2, channel quad q4 = w&3
  {
    const int ii = w >> 2, q4 = w & 3;
    const float4* rp = (const float4*)(rel + ((size_t)(b * NN + i0 + ii)) * (NN * RL));
    #pragma unroll
    for (int m = 0; m < 4; ++m) {
      const int j = l + 64 * m;
      float4 v = rp[j * 4 + q4];
      rldsT[(ii * RL + 4 * q4 + 0) * RLT + j] = v.x;
      rldsT[(ii * RL + 4 * q4 + 1) * RLT + j] = v.y;
      rldsT[(ii * RL + 4 * q4 + 2) * RLT + j] = v.z;
      rldsT[(ii * RL + 4 * q4 + 3) * RLT + j] = v.w;
    }
  }

  // ======== GRID BARRIER (all 512 blocks co-resident by construction) ========
  __syncthreads();
  if (tid == 0) {
    __threadfence();   // release this block's ws stores (flush XCD L2)
    __hip_atomic_fetch_add(syncp, 1u, __ATOMIC_ACQ_REL, __HIP_MEMORY_SCOPE_AGENT);
    while (__hip_atomic_load(syncp, __ATOMIC_ACQUIRE, __HIP_MEMORY_SCOPE_AGENT) < NBLK) {
      __builtin_amdgcn_s_sleep(2);
    }
    __threadfence();   // acquire: invalidate caches before consuming
  }
  __syncthreads();

  // ======== ATTENTION (r6 structure; q pre-scaled, qrs/rldsT ready) ========
  // phase A: scores for head w, j = {2l, 2l+1, 2l+128, 2l+129}
  float s[2][4] = {{0.f,0.f,0.f,0.f},{0.f,0.f,0.f,0.f}};
  {
    const ushort2* krow = (const ushort2*)(KnB + ((size_t)b * FD + w * HD) * NN);
    const float* q0 = &q[0][w * HD];
    const float* q1 = &q[1][w * HD];
    #pragma unroll 4
    for (int d = 0; d < HD; ++d) {
      ushort2 ua = krow[d * 128 + l];
      ushort2 ub = krow[d * 128 + 64 + l];
      float k0 = bf2f(ua.x), k1 = bf2f(ua.y), k2 = bf2f(ub.x), k3 = bf2f(ub.y);
      float qa = q0[d], qb = q1[d];
      s[0][0] += qa * k0; s[0][1] += qa * k1; s[0][2] += qa * k2; s[0][3] += qa * k3;
      s[1][0] += qb * k0; s[1][1] += qb * k1; s[1][2] += qb * k2; s[1][3] += qb * k3;
    }
  }
  // rel-term: s += qrs[h=w][r] * relT[r][j]
  #pragma unroll
  for (int ii = 0; ii < 2; ++ii) {
    #pragma unroll
    for (int r = 0; r < RL; ++r) {
      const float qv = qrs[ii][w * RL + r];
      const float* rr = &rldsT[(ii * RL + r) * RLT];
      float2 ra = *(const float2*)&rr[2 * l];
      float2 rb = *(const float2*)&rr[2 * l + 128];
      s[ii][0] += qv * ra.x; s[ii][1] += qv * ra.y;
      s[ii][2] += qv * rb.x; s[ii][3] += qv * rb.y;
    }
  }
  // phase B: within-wave softmax
  #pragma unroll
  for (int ii = 0; ii < 2; ++ii) {
    float v = fmaxf(fmaxf(s[ii][0], s[ii][1]), fmaxf(s[ii][2], s[ii][3]));
    #pragma unroll
    for (int off = 32; off; off >>= 1) v = fmaxf(v, __shfl_xor(v, off));
    float p0 = __expf(s[ii][0] - v), p1 = __expf(s[ii][1] - v);
    float p2 = __expf(s[ii][2] - v), p3 = __expf(s[ii][3] - v);
    float sum = p0 + p1 + p2 + p3;
    #pragma unroll
    for (int off = 32; off; off >>= 1) sum += __shfl_xor(sum, off);
    const float rec = 1.f / sum;
    *(float2*)&at[(ii * NH + w) * ATP + 2 * l]       = make_float2(p0 * rec, p1 * rec);
    *(float2*)&at[(ii * NH + w) * ATP + 2 * l + 128] = make_float2(p2 * rec, p3 * rec);
  }
  // phase C: ar[ii][w][r] = sum_j at[w][j] * relT[r][j]   (wave-local at)
  #pragma unroll
  for (int ii = 0; ii < 2; ++ii) {
    const int r = l & 15, q4 = l >> 4;
    const float* arow = &at[(ii * NH + w) * ATP];
    const float* rrow = &rldsT[(ii * RL + r) * RLT];
    float a = 0.f;
    #pragma unroll 4
    for (int jj = 0; jj < 64; ++jj) {
      const int j = 4 * jj + q4;
      a += arow[j] * rrow[j];
    }
    a += __shfl_xor(a, 16);
    a += __shfl_xor(a, 32);
    if (l < 16) ar[ii][w * RL + l] = a;
  }
  __syncthreads();   // all heads' at + ar visible; rldsT dead -> part alias

  // phase D: partial wv over j in [32w, 32w+32); c = {2l,2l+1,2l+128,2l+129}
  {
    const int h = l >> 4;
    const ushort2* vrow = (const ushort2*)(VnB + (size_t)b * NN * FD);
    float a00=0.f,a01=0.f,a02=0.f,a03=0.f, a10=0.f,a11=0.f,a12=0.f,a13=0.f;
    #pragma unroll 4
    for (int jj = 0; jj < 32; ++jj) {
      const int j = 32 * w + jj;
      ushort2 ua = vrow[j * 128 + l];
      ushort2 ub = vrow[j * 128 + 64 + l];
      float v0 = bf2f(ua.x), v1 = bf2f(ua.y), v2 = bf2f(ub.x), v3 = bf2f(ub.y);
      float p0  = at[h * ATP + j];
      float p0b = at[(h + 4) * ATP + j];
      float p1  = at[(NH + h) * ATP + j];
      float p1b = at[(NH + h + 4) * ATP + j];
      a00 += p0 * v0;  a01 += p0 * v1;  a02 += p0b * v2; a03 += p0b * v3;
      a10 += p1 * v0;  a11 += p1 * v1;  a12 += p1b * v2; a13 += p1b * v3;
    }
    *(float2*)&part[(0 * NH + w) * 256 + 2 * l]       = make_float2(a00, a01);
    *(float2*)&part[(0 * NH + w) * 256 + 2 * l + 128] = make_float2(a02, a03);
    *(float2*)&part[(1 * NH + w) * 256 + 2 * l]       = make_float2(a10, a11);
    *(float2*)&part[(1 * NH + w) * 256 + 2 * l + 128] = make_float2(a12, a13);
  }
  __syncthreads();

  // phase E: reduce 8 wave-partials + Wv_r term -> wvT[c][ii]
  {
    const int ii = tid >> 8, c = tid & 255, h2 = c >> 5;
    float sE = 0.f;
    #pragma unroll
    for (int w2 = 0; w2 < 8; ++w2) sE += part[(ii * NH + w2) * 256 + c];
    #pragma unroll
    for (int r = 0; r < RL; ++r)
      sE += ar[ii][h2 * RL + r] * Wv[(FD + r) * FD + c];
    wvT[c * 2 + ii] = sE;
  }
  __syncthreads();

  // phase F: out = nf + wv @ Wo + bo  (packed bf16 Wo, nf from LDS)
  {
    const int ii = tid >> 8, c = tid & 255;
    float acc = 0.f;
    #pragma unroll 8
    for (int k2 = 0; k2 < 128; ++k2) {
      unsigned int u = WoP[k2 * FD + c];
      float w0 = bf2f((unsigned short)(u & 0xffffu));
      float w1 = bf2f((unsigned short)(u >> 16));
      acc += wvT[(2 * k2) * 2 + ii] * w0 + wvT[(2 * k2 + 1) * 2 + ii] * w1;
    }
    const int row = b * NN + i0 + ii;
    out[row * FD + c] = nfT[c][ii] + acc + bo[c];
  }
}

extern "C" void kernel_launch(void* const* d_in, const int* in_sizes, int n_in,
                              void* d_out, int out_size, void* d_ws, size_t ws_size,
                              hipStream_t stream) {
  const float* nf  = (const float*)d_in[0];
  const float* rel = (const float*)d_in[1];
  const float* Wq  = (const float*)d_in[2];
  const float* bq  = (const float*)d_in[3];
  const float* Wk  = (const float*)d_in[4];
  const float* bk  = (const float*)d_in[5];
  const float* Wv  = (const float*)d_in[6];
  const float* bv  = (const float*)d_in[7];
  const float* Wo  = (const float*)d_in[8];
  const float* bo  = (const float*)d_in[9];
  float* out = (float*)d_out;
  float* ws  = (float*)d_ws;

  // zero the grid-barrier counter (captured memset node; deterministic per replay)
  hipMemsetAsync((char*)d_ws + (size_t)OFF_SYNC * 4, 0, 64, stream);
  k_fused<<<NBLK, 512, 0, stream>>>(nf, rel, Wq, bq, Wk, bk, Wv, bv, Wo, bo, out, ws);
}

// Round 8
// 87.028 us; speedup vs baseline: 1.4862x; 1.4862x over previous
//
#include <hip/hip_runtime.h>

// GeometricAttention: B=4, N=256, FDIM=256, REL=16, H=8, D=32
//   K[b,i,j] = Kn[b,j] + rel[b,i,j] @ Wk_r          (Kn = nf@Wk_f + bk)
//   scores   = Q.Kn^T + Qr.rel^T                     (Qr = per-head Q @ Wk_r^T)
//   sum_j attn*V = attn@Vn + (attn@rel)@Wv_r         (Vn = nf@Wv_f + bv)
// Round 8: r7 single-kernel structure, FIXED grid-barrier protocol:
//   - producers use nontemporal stores (data lands at Infinity Cache, no dirty L2)
//   - spin uses RELAXED atomic loads (r7's per-poll ACQUIRE emitted an L2
//     invalidate per iteration -> 512-block inv storm -> 115us of stall)
//   - single acquire __threadfence after spin; consumers use cached loads.

#define BB 4
#define NN 256
#define FD 256
#define RL 16
#define NH 8
#define HD 32
#define NBLK 512

// ws layout (float offsets)
#define OFF_KN   0                        // ushort KnT[b][f][j]   (512 KB)
#define OFF_VN   (BB*NN*FD/2)             // ushort Vn[b][j][c]    (512 KB)
#define OFF_WO   (OFF_VN + BB*NN*FD/2)    // uint WoP[128][256]    (128 KB)
#define OFF_SYNC (OFF_WO + FD*FD/2)       // unsigned counter

#define ATP 260   // at[] row stride (floats)
#define RLT 262   // rldsT row stride; 262%32=6 -> 16 r-lanes hit distinct banks

static __device__ __forceinline__ unsigned short f2bf(float x) {
  unsigned int u = __float_as_uint(x);
  unsigned int r = (u + 0x7fffu + ((u >> 16) & 1u)) >> 16;   // RNE
  return (unsigned short)r;
}
static __device__ __forceinline__ float bf2f(unsigned short h) {
  return __uint_as_float(((unsigned int)h) << 16);
}

__global__ __launch_bounds__(512, 4) void k_fused(
    const float* __restrict__ nf, const float* __restrict__ rel,
    const float* __restrict__ Wq, const float* __restrict__ bq,
    const float* __restrict__ Wk, const float* __restrict__ bk,
    const float* __restrict__ Wv, const float* __restrict__ bv,
    const float* __restrict__ Wo, const float* __restrict__ bo,
    float* __restrict__ out, float* __restrict__ ws) {
  const unsigned short* KnB = (const unsigned short*)(ws + OFF_KN);
  const unsigned short* VnB = (const unsigned short*)(ws + OFF_VN);
  const unsigned int* WoP = (const unsigned int*)(ws + OFF_WO);
  unsigned int* syncp = (unsigned int*)(ws + OFF_SYNC);

  // XCD-chunked swizzle (bijective, 512 % 8 == 0)
  const int bid = (blockIdx.x & 7) * 64 + (blockIdx.x >> 3);
  const int b  = bid >> 7;
  const int i0 = (bid & 127) * 2;
  const int tid = threadIdx.x;
  const int l = tid & 63, w = tid >> 6;

  __shared__ float nfT[FD][2];                         // 2 KB   [k][r]
  __shared__ float q[2][FD];                           // 2 KB   scaled
  __shared__ float qrs[2][NH * RL];                    // 1 KB
  __shared__ __align__(16) float rldsT[2 * RL * RLT];  // 32.8 KB (aliased later)
  __shared__ __align__(16) float at[2 * NH * ATP];     // 16.3 KB (red during proj)
  __shared__ float ar[2][NH * RL];                     // 1 KB
  float* red  = at;                                    // [6][256] proj reduce
  float* part = rldsT;                                 // [16][256] after phase C
  float* wvT  = rldsT + 16 * 256;                      // [256][2]

  // ======== PROJECTION: this block's 2 rows through Wq/Wk/Wv ========
  {
    const int r0 = tid >> 8, k0 = tid & 255;
    nfT[k0][r0] = nf[(b * NN + i0 + r0) * FD + k0];
  }
  __syncthreads();
  const int col = tid & 255, half = tid >> 8;
  float aq0=0.f,aq1=0.f,ak0=0.f,ak1=0.f,av0=0.f,av1=0.f;
  {
    const float* wqp = Wq + (half * 128) * FD + col;
    const float* wkp = Wk + (half * 128) * FD + col;
    const float* wvp = Wv + (half * 128) * FD + col;
    const float* np  = &nfT[half * 128][0];
    #pragma unroll 8
    for (int kk = 0; kk < 128; ++kk) {
      float2 nv = *(const float2*)&np[kk * 2];
      float wq_ = wqp[kk * FD], wk_ = wkp[kk * FD], wv_ = wvp[kk * FD];
      aq0 += nv.x * wq_; aq1 += nv.y * wq_;
      ak0 += nv.x * wk_; ak1 += nv.y * wk_;
      av0 += nv.x * wv_; av1 += nv.y * wv_;
    }
  }
  __syncthreads();                 // nfT k-loop reads done; red aliases at
  if (half) {
    red[0*256+col]=aq0; red[1*256+col]=aq1;
    red[2*256+col]=ak0; red[3*256+col]=ak1;
    red[4*256+col]=av0; red[5*256+col]=av1;
  }
  __syncthreads();
  if (!half) {
    const float scale = 0.17677669529663687f;   // 1/sqrt(32)
    aq0 += red[0*256+col]; aq1 += red[1*256+col];
    ak0 += red[2*256+col]; ak1 += red[3*256+col];
    av0 += red[4*256+col]; av1 += red[5*256+col];
    q[0][col] = (aq0 + bq[col]) * scale;
    q[1][col] = (aq1 + bq[col]) * scale;
    const float bkc = bk[col];
    unsigned int kp = (unsigned int)f2bf(ak0 + bkc)
                    | ((unsigned int)f2bf(ak1 + bkc) << 16);
    __builtin_nontemporal_store(kp,
      &((unsigned int*)(ws + OFF_KN))[((size_t)b * FD + col) * (NN/2) + (i0 >> 1)]);
    const float bvc = bv[col];
    unsigned short* vp = (unsigned short*)(ws + OFF_VN);
    __builtin_nontemporal_store(f2bf(av0 + bvc), &vp[((size_t)b * NN + i0)     * FD + col]);
    __builtin_nontemporal_store(f2bf(av1 + bvc), &vp[((size_t)b * NN + i0 + 1) * FD + col]);
  }
  // WoP pack: first 128 raw blocks, 2 Wo rows each
  if (blockIdx.x < 128 && tid < 256) {
    const int k2 = blockIdx.x;
    unsigned int lo = f2bf(Wo[(2 * k2) * FD + tid]);
    unsigned int hi = f2bf(Wo[(2 * k2 + 1) * FD + tid]);
    __builtin_nontemporal_store(lo | (hi << 16),
      &((unsigned int*)(ws + OFF_WO))[k2 * FD + tid]);
  }
  __syncthreads();                 // q visible block-wide

  // ---- pre-barrier (overlaps other blocks' projections):
  // qr[ii][h][r] = q[ii][h*32..] . Wk_r rows
  if (tid < 256) {
    const int ii = tid >> 7, h = (tid >> 4) & 7, r = tid & 15;
    const float* wrow = Wk + (FD + r) * FD + h * HD;
    const float* qq = &q[ii][h * HD];
    float a = 0.f;
    #pragma unroll
    for (int d = 0; d < HD; ++d) a += qq[d] * wrow[d];
    qrs[ii][h * RL + r] = a;
  }
  // stage rel transposed: wave w -> row ii = w>>2, channel quad q4 = w&3
  {
    const int ii = w >> 2, q4 = w & 3;
    const float4* rp = (const float4*)(rel + ((size_t)(b * NN + i0 + ii)) * (NN * RL));
    #pragma unroll
    for (int m = 0; m < 4; ++m) {
      const int j = l + 64 * m;
      float4 v = rp[j * 4 + q4];
      rldsT[(ii * RL + 4 * q4 + 0) * RLT + j] = v.x;
      rldsT[(ii * RL + 4 * q4 + 1) * RLT + j] = v.y;
      rldsT[(ii * RL + 4 * q4 + 2) * RLT + j] = v.z;
      rldsT[(ii * RL + 4 * q4 + 3) * RLT + j] = v.w;
    }
  }

  // ======== GRID BARRIER ========
  // All 512 blocks co-resident (2/CU by launch_bounds+LDS). __syncthreads
  // already drained each wave's nt-stores (vmcnt 0) -> data is at the
  // coherence point. RELAXED spin (no per-poll cache inv!), one acquire
  // fence after release.
  __syncthreads();
  if (tid == 0) {
    __hip_atomic_fetch_add(syncp, 1u, __ATOMIC_RELAXED, __HIP_MEMORY_SCOPE_AGENT);
    while (__hip_atomic_load(syncp, __ATOMIC_RELAXED, __HIP_MEMORY_SCOPE_AGENT) < NBLK) {
      __builtin_amdgcn_s_sleep(8);
    }
    __threadfence();   // one-time acquire: invalidate stale L2 before consuming
  }
  __syncthreads();

  // ======== ATTENTION (identical to r7) ========
  // phase A: scores for head w, j = {2l, 2l+1, 2l+128, 2l+129}
  float s[2][4] = {{0.f,0.f,0.f,0.f},{0.f,0.f,0.f,0.f}};
  {
    const ushort2* krow = (const ushort2*)(KnB + ((size_t)b * FD + w * HD) * NN);
    const float* q0 = &q[0][w * HD];
    const float* q1 = &q[1][w * HD];
    #pragma unroll 4
    for (int d = 0; d < HD; ++d) {
      ushort2 ua = krow[d * 128 + l];
      ushort2 ub = krow[d * 128 + 64 + l];
      float k0 = bf2f(ua.x), k1 = bf2f(ua.y), k2 = bf2f(ub.x), k3 = bf2f(ub.y);
      float qa = q0[d], qb = q1[d];
      s[0][0] += qa * k0; s[0][1] += qa * k1; s[0][2] += qa * k2; s[0][3] += qa * k3;
      s[1][0] += qb * k0; s[1][1] += qb * k1; s[1][2] += qb * k2; s[1][3] += qb * k3;
    }
  }
  // rel-term: s += qrs[h=w][r] * relT[r][j]
  #pragma unroll
  for (int ii = 0; ii < 2; ++ii) {
    #pragma unroll
    for (int r = 0; r < RL; ++r) {
      const float qv = qrs[ii][w * RL + r];
      const float* rr = &rldsT[(ii * RL + r) * RLT];
      float2 ra = *(const float2*)&rr[2 * l];
      float2 rb = *(const float2*)&rr[2 * l + 128];
      s[ii][0] += qv * ra.x; s[ii][1] += qv * ra.y;
      s[ii][2] += qv * rb.x; s[ii][3] += qv * rb.y;
    }
  }
  // phase B: within-wave softmax
  #pragma unroll
  for (int ii = 0; ii < 2; ++ii) {
    float v = fmaxf(fmaxf(s[ii][0], s[ii][1]), fmaxf(s[ii][2], s[ii][3]));
    #pragma unroll
    for (int off = 32; off; off >>= 1) v = fmaxf(v, __shfl_xor(v, off));
    float p0 = __expf(s[ii][0] - v), p1 = __expf(s[ii][1] - v);
    float p2 = __expf(s[ii][2] - v), p3 = __expf(s[ii][3] - v);
    float sum = p0 + p1 + p2 + p3;
    #pragma unroll
    for (int off = 32; off; off >>= 1) sum += __shfl_xor(sum, off);
    const float rec = 1.f / sum;
    *(float2*)&at[(ii * NH + w) * ATP + 2 * l]       = make_float2(p0 * rec, p1 * rec);
    *(float2*)&at[(ii * NH + w) * ATP + 2 * l + 128] = make_float2(p2 * rec, p3 * rec);
  }
  // phase C: ar[ii][w][r] = sum_j at[w][j] * relT[r][j]   (wave-local at)
  #pragma unroll
  for (int ii = 0; ii < 2; ++ii) {
    const int r = l & 15, q4 = l >> 4;
    const float* arow = &at[(ii * NH + w) * ATP];
    const float* rrow = &rldsT[(ii * RL + r) * RLT];
    float a = 0.f;
    #pragma unroll 4
    for (int jj = 0; jj < 64; ++jj) {
      const int j = 4 * jj + q4;
      a += arow[j] * rrow[j];
    }
    a += __shfl_xor(a, 16);
    a += __shfl_xor(a, 32);
    if (l < 16) ar[ii][w * RL + l] = a;
  }
  __syncthreads();   // all heads' at + ar visible; rldsT dead -> part alias

  // phase D: partial wv over j in [32w, 32w+32); c = {2l,2l+1,2l+128,2l+129}
  {
    const int h = l >> 4;
    const ushort2* vrow = (const ushort2*)(VnB + (size_t)b * NN * FD);
    float a00=0.f,a01=0.f,a02=0.f,a03=0.f, a10=0.f,a11=0.f,a12=0.f,a13=0.f;
    #pragma unroll 4
    for (int jj = 0; jj < 32; ++jj) {
      const int j = 32 * w + jj;
      ushort2 ua = vrow[j * 128 + l];
      ushort2 ub = vrow[j * 128 + 64 + l];
      float v0 = bf2f(ua.x), v1 = bf2f(ua.y), v2 = bf2f(ub.x), v3 = bf2f(ub.y);
      float p0  = at[h * ATP + j];
      float p0b = at[(h + 4) * ATP + j];
      float p1  = at[(NH + h) * ATP + j];
      float p1b = at[(NH + h + 4) * ATP + j];
      a00 += p0 * v0;  a01 += p0 * v1;  a02 += p0b * v2; a03 += p0b * v3;
      a10 += p1 * v0;  a11 += p1 * v1;  a12 += p1b * v2; a13 += p1b * v3;
    }
    *(float2*)&part[(0 * NH + w) * 256 + 2 * l]       = make_float2(a00, a01);
    *(float2*)&part[(0 * NH + w) * 256 + 2 * l + 128] = make_float2(a02, a03);
    *(float2*)&part[(1 * NH + w) * 256 + 2 * l]       = make_float2(a10, a11);
    *(float2*)&part[(1 * NH + w) * 256 + 2 * l + 128] = make_float2(a12, a13);
  }
  __syncthreads();

  // phase E: reduce 8 wave-partials + Wv_r term -> wvT[c][ii]
  {
    const int ii = tid >> 8, c = tid & 255, h2 = c >> 5;
    float sE = 0.f;
    #pragma unroll
    for (int w2 = 0; w2 < 8; ++w2) sE += part[(ii * NH + w2) * 256 + c];
    #pragma unroll
    for (int r = 0; r < RL; ++r)
      sE += ar[ii][h2 * RL + r] * Wv[(FD + r) * FD + c];
    wvT[c * 2 + ii] = sE;
  }
  __syncthreads();

  // phase F: out = nf + wv @ Wo + bo  (packed bf16 Wo, nf from LDS)
  {
    const int ii = tid >> 8, c = tid & 255;
    float acc = 0.f;
    #pragma unroll 8
    for (int k2 = 0; k2 < 128; ++k2) {
      unsigned int u = WoP[k2 * FD + c];
      float w0 = bf2f((unsigned short)(u & 0xffffu));
      float w1 = bf2f((unsigned short)(u >> 16));
      acc += wvT[(2 * k2) * 2 + ii] * w0 + wvT[(2 * k2 + 1) * 2 + ii] * w1;
    }
    const int row = b * NN + i0 + ii;
    out[row * FD + c] = nfT[c][ii] + acc + bo[c];
  }
}

extern "C" void kernel_launch(void* const* d_in, const int* in_sizes, int n_in,
                              void* d_out, int out_size, void* d_ws, size_t ws_size,
                              hipStream_t stream) {
  const float* nf  = (const float*)d_in[0];
  const float* rel = (const float*)d_in[1];
  const float* Wq  = (const float*)d_in[2];
  const float* bq  = (const float*)d_in[3];
  const float* Wk  = (const float*)d_in[4];
  const float* bk  = (const float*)d_in[5];
  const float* Wv  = (const float*)d_in[6];
  const float* bv  = (const float*)d_in[7];
  const float* Wo  = (const float*)d_in[8];
  const float* bo  = (const float*)d_in[9];
  float* out = (float*)d_out;
  float* ws  = (float*)d_ws;

  // zero the grid-barrier counter (captured memset node; deterministic per replay)
  hipMemsetAsync((char*)d_ws + (size_t)OFF_SYNC * 4, 0, 64, stream);
  k_fused<<<NBLK, 512, 0, stream>>>(nf, rel, Wq, bq, Wk, bk, Wv, bv, Wo, bo, out, ws);
}

// Round 9
// 43.400 us; speedup vs baseline: 2.9801x; 2.0052x over previous
//
#include <hip/hip_runtime.h>

// GeometricAttention: B=4, N=256, FDIM=256, REL=16, H=8, D=32
//   K[b,i,j] = Kn[b,j] + rel[b,i,j] @ Wk_r          (Kn = nf@Wk_f + bk)
//   scores   = Q.Kn^T + Qr.rel^T                     (Qr = per-head Q @ Wk_r^T)
//   sum_j attn*V = attn@Vn + (attn@rel)@Wv_r         (Vn = nf@Wv_f + bv)
// Round 9: revert to r5 two-kernel structure (41.6us known-good); LDS diet on
// k_attn (rel bf16-transposed-packed 16.6KB, part/wvT aliased) -> 37KB ->
// 4 blocks/CU (was 2); k_qkv ROWS=4 -> 1024 blocks, 4/CU (was 1.5); Wo packed
// bf16 in producer. Persistent-kernel branch abandoned (r7/r8 falsified).

#define BB 4
#define NN 256
#define FD 256
#define RL 16
#define NH 8
#define HD 32

// ws layout (float offsets)
#define OFF_Q    0                        // float Q[b][i][f]
#define OFF_KN   (BB*NN*FD)               // ushort KnT[b][f][j]
#define OFF_VN   (OFF_KN + BB*NN*FD/2)    // ushort Vn[b][j][c]
#define OFF_WO   (OFF_VN + BB*NN*FD/2)    // uint WoP[128][256] (bf16 pairs along k)

#define ATP 260   // at[] row stride (floats)
#define RLT 130   // rldsT row stride (uints); row base even -> uint2 aligned

static __device__ __forceinline__ unsigned short f2bf(float x) {
  unsigned int u = __float_as_uint(x);
  unsigned int r = (u + 0x7fffu + ((u >> 16) & 1u)) >> 16;   // RNE
  return (unsigned short)r;
}
static __device__ __forceinline__ float bf2f(unsigned short h) {
  return __uint_as_float(((unsigned int)h) << 16);
}

// ---------------- Kernel 1: Q(fp32) / KnT(bf16,T) / Vn(bf16) / WoP
__global__ __launch_bounds__(256, 4) void k_qkv9(
    const float* __restrict__ nf,
    const float* __restrict__ Wq, const float* __restrict__ bq,
    const float* __restrict__ Wk, const float* __restrict__ bk,
    const float* __restrict__ Wv, const float* __restrict__ bv,
    const float* __restrict__ Wo,
    float* __restrict__ ws) {
  const int tid = threadIdx.x;
  const int sel = blockIdx.y;          // 0=Q, 1=KnT, 2=Vn, 3=WoP
  if (sel == 3) {
    if (blockIdx.x < 128) {
      const int k2 = blockIdx.x;       // Wo rows 2k2, 2k2+1
      unsigned int lo = f2bf(Wo[(2 * k2) * FD + tid]);
      unsigned int hi = f2bf(Wo[(2 * k2 + 1) * FD + tid]);
      ((unsigned int*)(ws + OFF_WO))[k2 * FD + tid] = lo | (hi << 16);
    }
    return;
  }
  const int ROWS = 4;
  __shared__ float lrowT[FD][ROWS];    // [k][r]; k-loop reads are broadcasts
  const int row0 = blockIdx.x * ROWS;
  const float* W; const float* bias;
  if (sel == 0)      { W = Wq; bias = bq; }
  else if (sel == 1) { W = Wk; bias = bk; }
  else               { W = Wv; bias = bv; }
  #pragma unroll
  for (int t = 0; t < ROWS; ++t)
    lrowT[tid][t] = nf[(row0 + t) * FD + tid];
  __syncthreads();
  float acc[ROWS] = {0.f, 0.f, 0.f, 0.f};
  #pragma unroll 16
  for (int k = 0; k < FD; ++k) {
    const float w = W[k * FD + tid];
    float4 a0 = *(const float4*)&lrowT[k][0];
    acc[0] += a0.x * w; acc[1] += a0.y * w; acc[2] += a0.z * w; acc[3] += a0.w * w;
  }
  const float bb = bias[tid];
  if (sel == 1) {
    const int b2 = row0 >> 8, i0 = row0 & 255;
    unsigned short* kout = (unsigned short*)(ws + OFF_KN) + ((size_t)b2 * FD + tid) * NN + i0;
    ushort4 v0;
    v0.x = f2bf(acc[0] + bb); v0.y = f2bf(acc[1] + bb);
    v0.z = f2bf(acc[2] + bb); v0.w = f2bf(acc[3] + bb);
    *((ushort4*)kout) = v0;
  } else if (sel == 2) {
    unsigned short* outp = (unsigned short*)(ws + OFF_VN);
    #pragma unroll
    for (int r = 0; r < ROWS; ++r)
      outp[(size_t)(row0 + r) * FD + tid] = f2bf(acc[r] + bb);
  } else {
    float* outp = ws + OFF_Q;
    #pragma unroll
    for (int r = 0; r < ROWS; ++r)
      outp[(row0 + r) * FD + tid] = acc[r] + bb;
  }
}

// ---------------- Kernel 2: qr + scores + softmax + arel + wv + output
// 2 Q-rows/block; 256 thr; wave w owns heads {2w,2w+1}; j = 4l..4l+3.
__global__ __launch_bounds__(256, 4) void k_attn9(
    const float* __restrict__ rel,
    const float* __restrict__ Wk,
    const float* __restrict__ Wv,
    const float* __restrict__ nf,
    const float* __restrict__ bo,
    float* __restrict__ out,
    float* __restrict__ ws) {
  const float* Q = ws + OFF_Q;
  const unsigned short* KnB = (const unsigned short*)(ws + OFF_KN);
  const unsigned short* VnB = (const unsigned short*)(ws + OFF_VN);
  const unsigned int* WoP = (const unsigned int*)(ws + OFF_WO);

  // XCD-chunked swizzle over 512 blocks (bijective)
  const int bid = (blockIdx.x & 7) * 64 + (blockIdx.x >> 3);
  const int b  = bid >> 7;
  const int i0 = (bid & 127) * 2;
  const int tid = threadIdx.x;
  const int l = tid & 63, w = tid >> 6;

  __shared__ float q[2][FD];                            // 2 KB (scaled)
  __shared__ float qrs[2][NH * RL];                     // 1 KB
  __shared__ float ar[2][NH * RL];                      // 1 KB
  __shared__ __align__(16) float at[2 * NH * ATP];      // 16.6 KB
  __shared__ __align__(16) unsigned int rldsT[2 * RL * RLT];  // 16.6 KB bf16 relT
  float* part = (float*)rldsT;                          // [2][4][256] after C
  float* wvT  = (float*)rldsT + 2048;                   // [256][2]

  const float scale = 0.17677669529663687f;  // 1/sqrt(32)
  q[0][tid] = Q[(b * NN + i0) * FD + tid] * scale;
  q[1][tid] = Q[(b * NN + i0 + 1) * FD + tid] * scale;

  // stage rel transposed + bf16-packed: rldsT[(ii*RL + r)*RLT + jp] holds
  // (rel[r][2jp], rel[r][2jp+1]); conflict-free stores (8q4+jp distinct mod 32)
  #pragma unroll
  for (int ii = 0; ii < 2; ++ii) {
    const float4* rp = (const float4*)(rel + ((size_t)(b * NN + i0 + ii)) * (NN * RL));
    #pragma unroll
    for (int m = 0; m < 2; ++m) {
      const int t = tid + 256 * m;       // 0..511
      const int jp = t >> 2, q4 = t & 3;
      float4 va = rp[8 * jp + q4];       // j = 2jp
      float4 vb = rp[8 * jp + 4 + q4];   // j = 2jp+1
      unsigned int* base = &rldsT[(ii * RL + 4 * q4) * RLT + jp];
      base[0]       = (unsigned int)f2bf(va.x) | ((unsigned int)f2bf(vb.x) << 16);
      base[RLT]     = (unsigned int)f2bf(va.y) | ((unsigned int)f2bf(vb.y) << 16);
      base[2 * RLT] = (unsigned int)f2bf(va.z) | ((unsigned int)f2bf(vb.z) << 16);
      base[3 * RLT] = (unsigned int)f2bf(va.w) | ((unsigned int)f2bf(vb.w) << 16);
    }
  }

  // qr for wave's two heads, both rows (wave-local q rows)
  {
    const int ii = l >> 5, hh = (l >> 4) & 1, r = l & 15;
    const int h = 2 * w + hh;
    const float* wrow = Wk + (FD + r) * FD + h * HD;
    const float* qq = &q[ii][h * HD];
    float a = 0.f;
    #pragma unroll
    for (int d = 0; d < HD; ++d) a += qq[d] * wrow[d];
    qrs[ii][h * RL + r] = a;
  }
  __syncthreads();   // rldsT cross-wave

  // ---- phase A: scores s[ii][hh][jj], j = 4l+jj, bf16 KnT
  float s[2][2][4];
  #pragma unroll
  for (int ii = 0; ii < 2; ++ii)
    #pragma unroll
    for (int hh = 0; hh < 2; ++hh)
      #pragma unroll
      for (int jj = 0; jj < 4; ++jj) s[ii][hh][jj] = 0.f;
  {
    const ushort4* kp = (const ushort4*)(KnB + ((size_t)b * FD + 64 * w) * NN) + l;
    #pragma unroll 2
    for (int dd = 0; dd < 8; ++dd) {
      float4 qv00 = *(const float4*)&q[0][64 * w + 4 * dd];
      float4 qv01 = *(const float4*)&q[0][64 * w + 32 + 4 * dd];
      float4 qv10 = *(const float4*)&q[1][64 * w + 4 * dd];
      float4 qv11 = *(const float4*)&q[1][64 * w + 32 + 4 * dd];
      #pragma unroll
      for (int e = 0; e < 4; ++e) {
        ushort4 u0 = kp[(4 * dd + e) * (NN / 4)];        // head 2w
        ushort4 u1 = kp[(32 + 4 * dd + e) * (NN / 4)];   // head 2w+1
        float4 k0 = make_float4(bf2f(u0.x), bf2f(u0.y), bf2f(u0.z), bf2f(u0.w));
        float4 k1 = make_float4(bf2f(u1.x), bf2f(u1.y), bf2f(u1.z), bf2f(u1.w));
        const float a0 = (&qv00.x)[e], a1 = (&qv01.x)[e];
        const float b0 = (&qv10.x)[e], b1 = (&qv11.x)[e];
        s[0][0][0] += a0 * k0.x; s[0][0][1] += a0 * k0.y;
        s[0][0][2] += a0 * k0.z; s[0][0][3] += a0 * k0.w;
        s[1][0][0] += b0 * k0.x; s[1][0][1] += b0 * k0.y;
        s[1][0][2] += b0 * k0.z; s[1][0][3] += b0 * k0.w;
        s[0][1][0] += a1 * k1.x; s[0][1][1] += a1 * k1.y;
        s[0][1][2] += a1 * k1.z; s[0][1][3] += a1 * k1.w;
        s[1][1][0] += b1 * k1.x; s[1][1][1] += b1 * k1.y;
        s[1][1][2] += b1 * k1.z; s[1][1][3] += b1 * k1.w;
      }
    }
  }

  // ---- rel-term: s += qr . relT  (uint2 reads, 2-way max)
  #pragma unroll
  for (int ii = 0; ii < 2; ++ii) {
    #pragma unroll
    for (int r = 0; r < RL; ++r) {
      uint2 u = *(const uint2*)&rldsT[(ii * RL + r) * RLT + 2 * l];
      float r0 = bf2f((unsigned short)(u.x & 0xffffu));
      float r1 = bf2f((unsigned short)(u.x >> 16));
      float r2 = bf2f((unsigned short)(u.y & 0xffffu));
      float r3 = bf2f((unsigned short)(u.y >> 16));
      const float qa = qrs[ii][(2 * w) * RL + r];
      const float qb = qrs[ii][(2 * w + 1) * RL + r];
      s[ii][0][0] += qa * r0; s[ii][0][1] += qa * r1;
      s[ii][0][2] += qa * r2; s[ii][0][3] += qa * r3;
      s[ii][1][0] += qb * r0; s[ii][1][1] += qb * r1;
      s[ii][1][2] += qb * r2; s[ii][1][3] += qb * r3;
    }
  }

  // ---- phase B: within-wave softmax (lane covers j = 4l..4l+3)
  #pragma unroll
  for (int ii = 0; ii < 2; ++ii) {
    #pragma unroll
    for (int hh = 0; hh < 2; ++hh) {
      float v = fmaxf(fmaxf(s[ii][hh][0], s[ii][hh][1]),
                      fmaxf(s[ii][hh][2], s[ii][hh][3]));
      #pragma unroll
      for (int off = 32; off; off >>= 1) v = fmaxf(v, __shfl_xor(v, off));
      float4 p;
      p.x = __expf(s[ii][hh][0] - v); p.y = __expf(s[ii][hh][1] - v);
      p.z = __expf(s[ii][hh][2] - v); p.w = __expf(s[ii][hh][3] - v);
      float sum = p.x + p.y + p.z + p.w;
      #pragma unroll
      for (int off = 32; off; off >>= 1) sum += __shfl_xor(sum, off);
      const float rec = 1.f / sum;
      p.x *= rec; p.y *= rec; p.z *= rec; p.w *= rec;
      *(float4*)&at[(ii * NH + 2 * w + hh) * ATP + 4 * l] = p;
    }
  }

  // ---- phase C: ar[ii][h][r] = sum_j at[h][j] * relT[r][j] (wave-local at)
  #pragma unroll
  for (int ii = 0; ii < 2; ++ii) {
    const int r = l & 15, sl = l >> 4;
    const int h = 2 * w + (sl & 1);
    const int jb = (sl >> 1) * 128;
    const float* atp = at + (ii * NH + h) * ATP + jb;
    const unsigned int* rr_ = &rldsT[(ii * RL + r) * RLT + (jb >> 1)];
    float a = 0.f;
    #pragma unroll 8
    for (int u = 0; u < 64; ++u) {
      unsigned int x = rr_[u];
      a += atp[2 * u]     * bf2f((unsigned short)(x & 0xffffu));
      a += atp[2 * u + 1] * bf2f((unsigned short)(x >> 16));
    }
    a += __shfl_xor(a, 32);
    if (l < 32) ar[ii][32 * w + l] = a;   // == ar[ii][h*16 + r]
  }
  __syncthreads();   // at cross-wave; rldsT dead -> part/wvT alias

  // ---- phase D: partial wv over j in [64w,64w+64); c = 4l..4l+3 (bf16 Vn)
  {
    const int h = l >> 3;                    // (4l) >> 5
    const ushort4* vp = (const ushort4*)(VnB + (size_t)b * NN * FD) + l;
    const float* ap0 = at + h * ATP + 64 * w;
    const float* ap1 = at + (NH + h) * ATP + 64 * w;
    float4 a0 = make_float4(0,0,0,0), a1 = make_float4(0,0,0,0);
    #pragma unroll 4
    for (int jj = 0; jj < 64; ++jj) {
      ushort4 u = vp[(64 * w + jj) * (FD / 4)];
      float4 v = make_float4(bf2f(u.x), bf2f(u.y), bf2f(u.z), bf2f(u.w));
      float p0 = ap0[jj], p1 = ap1[jj];
      a0.x += p0*v.x; a0.y += p0*v.y; a0.z += p0*v.z; a0.w += p0*v.w;
      a1.x += p1*v.x; a1.y += p1*v.y; a1.z += p1*v.z; a1.w += p1*v.w;
    }
    ((float4*)part)[w * 64 + l]       = a0;
    ((float4*)part)[(4 + w) * 64 + l] = a1;
  }
  __syncthreads();

  // ---- phase E: reduce partials + Wv_r term -> wvT[k][ii]
  {
    const int c = tid, h2 = c >> 5;
    float s0 = part[c] + part[FD + c] + part[2*FD + c] + part[3*FD + c];
    float s1 = part[4*FD + c] + part[5*FD + c] + part[6*FD + c] + part[7*FD + c];
    #pragma unroll
    for (int r = 0; r < RL; ++r) {
      const float wvr = Wv[(FD + r) * FD + c];
      s0 += ar[0][h2 * RL + r] * wvr;
      s1 += ar[1][h2 * RL + r] * wvr;
    }
    *(float2*)&wvT[2 * c] = make_float2(s0, s1);
  }
  __syncthreads();

  // ---- phase F: out = nf + wv @ Wo + bo (packed bf16 Wo; wvT broadcast reads)
  {
    const int c = tid;
    float acc0 = 0.f, acc1 = 0.f;
    #pragma unroll 8
    for (int k2 = 0; k2 < 128; ++k2) {
      unsigned int u = WoP[k2 * FD + c];
      float w0 = bf2f((unsigned short)(u & 0xffffu));
      float w1 = bf2f((unsigned short)(u >> 16));
      float2 wa = *(const float2*)&wvT[4 * k2];       // k = 2k2
      float2 wb = *(const float2*)&wvT[4 * k2 + 2];   // k = 2k2+1
      acc0 += wa.x * w0 + wb.x * w1;
      acc1 += wa.y * w0 + wb.y * w1;
    }
    const float bb = bo[c];
    const int row = b * NN + i0;
    out[row * FD + c]       = nf[row * FD + c]       + acc0 + bb;
    out[(row + 1) * FD + c] = nf[(row + 1) * FD + c] + acc1 + bb;
  }
}

extern "C" void kernel_launch(void* const* d_in, const int* in_sizes, int n_in,
                              void* d_out, int out_size, void* d_ws, size_t ws_size,
                              hipStream_t stream) {
  const float* nf  = (const float*)d_in[0];
  const float* rel = (const float*)d_in[1];
  const float* Wq  = (const float*)d_in[2];
  const float* bq  = (const float*)d_in[3];
  const float* Wk  = (const float*)d_in[4];
  const float* bk  = (const float*)d_in[5];
  const float* Wv  = (const float*)d_in[6];
  const float* bv  = (const float*)d_in[7];
  const float* Wo  = (const float*)d_in[8];
  const float* bo  = (const float*)d_in[9];
  float* out = (float*)d_out;
  float* ws  = (float*)d_ws;

  k_qkv9 <<<dim3(BB * NN / 4, 4), 256, 0, stream>>>(nf, Wq, bq, Wk, bk, Wv, bv, Wo, ws);
  k_attn9<<<BB * NN / 2, 256, 0, stream>>>(rel, Wk, Wv, nf, bo, out, ws);
}